// Round 6
// baseline (476.545 us; speedup 1.0000x reference)
//
#include <hip/hip_runtime.h>

#define T_STEPS 16
#define H 64
#define S_IN 25
#define A_OUT 4
#define NB 65536
#define EPW 16            // batch elements per wave (lane = hidden unit)
#define EPB 64            // batch elements per block (4 waves)

typedef unsigned long long ull;

__device__ __forceinline__ float fmaf_(float a, float b, float c) { return __builtin_fmaf(a, b, c); }

// Transpose W2 (64x64) and W3 (4x64) into workspace.
__global__ void snn_prep(const float* __restrict__ W2, const float* __restrict__ W3,
                         float* __restrict__ W2T, float* __restrict__ W3T) {
    int i = blockIdx.x * blockDim.x + threadIdx.x;
    if (i < H * H) { int h = i >> 6, k = i & 63; W2T[k * H + h] = W2[h * H + k]; }
    if (i < A_OUT * H) { int a = i >> 6, h = i & 63; W3T[h * A_OUT + a] = W3[a * H + h]; }
}

// lane = hidden unit; wave carries 16 elements' full state. Spike masks live
// in SGPRs via ballot; k-loop = 1 v_fma per (elem,k) with SALU bit-select
// co-issued. W2 rows broadcast from LDS with a 4-deep prefetch ring.
__global__ __launch_bounds__(256, 4) void snn_main(
    const float* __restrict__ x,
    const float* __restrict__ W1, const float* __restrict__ b1,
    const float* __restrict__ W2T, const float* __restrict__ b2,
    const float* __restrict__ W3T, const float* __restrict__ b3,
    float* __restrict__ out, int* __restrict__ g_pre, int* __restrict__ g_post)
{
#pragma clang fp contract(off)
    __shared__ float w2s[(H + 8) * H];          // [k][h], 8 pad rows for prefetch overrun
    __shared__ ull   s2m[2][EPB];               // per-slot per-element s2 masks
    __shared__ float m3acc[EPB][8];             // [elem][0..3]=m3, [4..7]=acc
    __shared__ int   lds_pre[T_STEPS][H];
    __shared__ int   lds_post[T_STEPS][A_OUT];

    for (int i = threadIdx.x; i < (H * H) / 4; i += 256)
        reinterpret_cast<float4*>(w2s)[i] = reinterpret_cast<const float4*>(W2T)[i];
    for (int i = threadIdx.x; i < T_STEPS * H; i += 256) (&lds_pre[0][0])[i] = 0;
    if (threadIdx.x < T_STEPS * A_OUT) (&lds_post[0][0])[threadIdx.x] = 0;
    for (int i = threadIdx.x; i < EPB * 8; i += 256) (&m3acc[0][0])[i] = 0.0f;
    __syncthreads();

    const int lane = threadIdx.x & 63;
    const int wq   = __builtin_amdgcn_readfirstlane(threadIdx.x >> 6);  // wave 0..3
    const int eb   = blockIdx.x * EPB + wq * EPW;                       // first element

    const float b1l = b1[lane];
    const float b2l = b2[lane];

    float cur1[EPW], m1[EPW], m2[EPW];
    {
        float w1l[S_IN];                        // W1 row for this lane's unit
        #pragma unroll
        for (int s = 0; s < S_IN; ++s) w1l[s] = W1[lane * S_IN + s];
        #pragma unroll
        for (int e = 0; e < EPW; ++e) {
            const float* xr = x + (size_t)(eb + e) * S_IN;   // uniform -> s_load
            float acc = 0.0f;
            #pragma unroll
            for (int s = 0; s < S_IN; ++s) acc = fmaf_(xr[s], w1l[s], acc);
            cur1[e] = acc + b1l;                // same s-chain as reference
            m1[e] = 0.0f; m2[e] = 0.0f;
        }
    }

    for (int t = 0; t < T_STEPS; ++t) {
        const int slot = t & 1;
        unsigned mlo = 0u, mhi = 0u;            // collected s2 masks (lanes 0..15)
        int cnt = 0;                            // spikes of unit `lane` over 16 elems

        #pragma unroll
        for (int g = 0; g < 2; ++g) {           // 8 elements at a time
            ull msk[8];
            // layer 1: membrane + spike; ballot IS the s1 mask (SGPR pair)
            #pragma unroll
            for (int e8 = 0; e8 < 8; ++e8) {
                const int e = g * 8 + e8;
                float m = 0.95f * m1[e];
                m = m + cur1[e];
                bool sp = m > 1.0f;
                msk[e8] = __ballot(sp);
                m1[e] = sp ? (m - 1.0f) : m;
                m2[e] = 0.95f * m2[e];
            }
            // layer 2: 8 interleaved exact k-chains, LDS-broadcast weights,
            // 4-deep prefetch ring covers ds_read latency.
            float wbuf[4];
            #pragma unroll
            for (int p = 0; p < 4; ++p) wbuf[p] = w2s[p * H + lane];
            for (int k = 0; k < H; k += 4) {
                #pragma unroll
                for (int p = 0; p < 4; ++p) {
                    const float wv = wbuf[p];
                    wbuf[p] = w2s[(k + 4 + p) * H + lane];    // pad rows absorb overrun
                    const ull kb = 1ull << (k + p);
                    #pragma unroll
                    for (int e8 = 0; e8 < 8; ++e8) {
                        const float sf = (msk[e8] & kb) ? 1.0f : 0.0f;  // s_and+s_cselect
                        m2[g * 8 + e8] = fmaf_(sf, wv, m2[g * 8 + e8]); // exact chain
                    }
                }
            }
            // layer-2 spikes: ballot = s2 mask; collect into lanes 0..15; count bits
            #pragma unroll
            for (int e8 = 0; e8 < 8; ++e8) {
                const int e = g * 8 + e8;
                float m = m2[e] + b2l;
                bool sp = m > 1.0f;
                ull s2 = __ballot(sp);
                m2[e] = sp ? (m - 1.0f) : m;
                mlo = (lane == e) ? (unsigned)s2 : mlo;
                mhi = (lane == e) ? (unsigned)(s2 >> 32) : mhi;
                cnt += (int)((s2 >> lane) & 1ull);     // exact integer count
            }
        }
        if (lane < EPW) s2m[slot][wq * EPW + lane] = ((ull)mhi << 32) | mlo;
        atomicAdd(&lds_pre[t][lane], cnt);
        __syncthreads();

        // layer 3: rotating duty wave, lane = block element, exact h-chain
        if (wq == (t & 3)) {
            ull s2v = s2m[slot][lane];
            float m3[A_OUT], ac[A_OUT];
            #pragma unroll
            for (int a = 0; a < A_OUT; ++a) { m3[a] = 0.95f * m3acc[lane][a]; ac[a] = m3acc[lane][4 + a]; }
            for (int h = 0; h < H; ++h) {
                float s2f = (float)((unsigned)s2v & 1u);
                s2v >>= 1;
                const float4 w = *reinterpret_cast<const float4*>(W3T + h * A_OUT);
                m3[0] = fmaf_(s2f, w.x, m3[0]);
                m3[1] = fmaf_(s2f, w.y, m3[1]);
                m3[2] = fmaf_(s2f, w.z, m3[2]);
                m3[3] = fmaf_(s2f, w.w, m3[3]);
            }
            int myPost = 0;
            #pragma unroll
            for (int a = 0; a < A_OUT; ++a) {
                float m = m3[a] + b3[a];
                bool sp = m > 1.0f;
                float s3f = sp ? 1.0f : 0.0f;
                m3[a] = m - s3f;
                ac[a] = ac[a] + s3f;
                int c = (int)__popcll(__ballot(sp));
                myPost = (lane == a) ? c : myPost;
            }
            if (lane < A_OUT) lds_post[t][lane] = myPost;
            if (t == T_STEPS - 1) {
                float r0 = ac[0] * 0.0625f, r1 = ac[1] * 0.0625f;
                float r2 = ac[2] * 0.0625f, r3 = ac[3] * 0.0625f;
                float mx = fmaxf(fmaxf(r0, r1), fmaxf(r2, r3));
                float e0 = expf(r0 - mx), e1 = expf(r1 - mx);
                float e2 = expf(r2 - mx), e3 = expf(r3 - mx);
                float s = ((e0 + e1) + e2) + e3;
                reinterpret_cast<float4*>(out)[blockIdx.x * EPB + lane] =
                    make_float4(e0 / s, e1 / s, e2 / s, e3 / s);
            } else {
                #pragma unroll
                for (int a = 0; a < A_OUT; ++a) { m3acc[lane][a] = m3[a]; m3acc[lane][4 + a] = ac[a]; }
            }
        }
    }

    __syncthreads();
    for (int i = threadIdx.x; i < T_STEPS * H; i += 256) atomicAdd(&g_pre[i], (&lds_pre[0][0])[i]);
    if (threadIdx.x < T_STEPS * A_OUT) atomicAdd(&g_post[threadIdx.x], (&lds_post[0][0])[threadIdx.x]);
}

// elig_t = 0.95*elig_{t-1} + (A_PLUS-A_MINUS) * outer(post_t, pre_t); exact counts/B.
__global__ void snn_elig(const int* __restrict__ g_pre, const int* __restrict__ g_post,
                         const float* __restrict__ elig0, float* __restrict__ out) {
#pragma clang fp contract(off)
    int i = threadIdx.x;                 // 256 = A_OUT * H
    int a = i >> 6, h = i & 63;
    float e = elig0[i];
    const float invB = 1.0f / 65536.0f;
    for (int t = 0; t < T_STEPS; ++t) {
        float pre  = (float)g_pre[t * H + h] * invB;
        float post = (float)g_post[t * A_OUT + a] * invB;
        e = 0.95f * e + (-0.002f) * (post * pre);
    }
    out[NB * A_OUT + i] = e;
}

extern "C" void kernel_launch(void* const* d_in, const int* in_sizes, int n_in,
                              void* d_out, int out_size, void* d_ws, size_t ws_size,
                              hipStream_t stream) {
    const float* x     = (const float*)d_in[0];
    const float* W1    = (const float*)d_in[1];
    const float* b1    = (const float*)d_in[2];
    const float* W2    = (const float*)d_in[3];
    const float* b2    = (const float*)d_in[4];
    const float* W3    = (const float*)d_in[5];
    const float* b3    = (const float*)d_in[6];
    const float* elig0 = (const float*)d_in[7];
    float* out = (float*)d_out;

    char* ws = (char*)d_ws;
    int*   g_pre  = (int*)(ws);                    // 1024 ints
    int*   g_post = (int*)(ws + 4096);             // 64 ints
    float* W2T    = (float*)(ws + 8192);           // 4096 floats
    float* W3T    = (float*)(ws + 8192 + 16384);   // 256 floats

    (void)hipMemsetAsync(ws, 0, 4096 + 256, stream);  // zero count accumulators every launch
    snn_prep<<<17, 256, 0, stream>>>(W2, W3, W2T, W3T);
    snn_main<<<NB / EPB, 256, 0, stream>>>(x, W1, b1, W2T, b2, W3T, b3, out, g_pre, g_post);
    snn_elig<<<1, 256, 0, stream>>>(g_pre, g_post, elig0, out);
}